// Round 1
// baseline (363.215 us; speedup 1.0000x reference)
//
#include <hip/hip_runtime.h>

typedef unsigned int uint32;

static constexpr int NCOL = 4096;       // last-dim size (fixed by problem)
static constexpr int THREADS = 256;     // 4 waves/block

// --- shared y computation: must be bit-identical between rowstats & output ---
__device__ __forceinline__ float norm_y(float x, float mu, float inv_std,
                                        float g, float b) {
    float xn = (x - mu) * inv_std;
    return xn * g + b;
}

__device__ __forceinline__ float wave_max_f(float m) {
    #pragma unroll
    for (int off = 32; off > 0; off >>= 1)
        m = fmaxf(m, __shfl_down(m, off));
    return m;
}

// ---------------- kernel 1: global amax(|x|) ----------------
__global__ void __launch_bounds__(THREADS) k_amax(const float* __restrict__ x,
                                                  long long n,
                                                  uint32* __restrict__ amax_bits) {
    long long i0 = ((long long)blockIdx.x * THREADS + threadIdx.x) * 4;
    long long stride = (long long)gridDim.x * THREADS * 4;
    float m = 0.0f;
    for (long long i = i0; i < n; i += stride) {
        const float4 v = *reinterpret_cast<const float4*>(x + i);
        m = fmaxf(m, fmaxf(fmaxf(fabsf(v.x), fabsf(v.y)),
                           fmaxf(fabsf(v.z), fabsf(v.w))));
    }
    m = wave_max_f(m);
    __shared__ float sm[THREADS / 64];
    const int lane = threadIdx.x & 63;
    const int w = threadIdx.x >> 6;
    if (lane == 0) sm[w] = m;
    __syncthreads();
    if (threadIdx.x == 0) {
        float bm = fmaxf(fmaxf(sm[0], sm[1]), fmaxf(sm[2], sm[3]));
        atomicMax(amax_bits, __float_as_uint(bm));
    }
}

// ---------------- kernel 2: per-row stats + global amax(|y|) ----------------
__global__ void __launch_bounds__(THREADS) k_rowstats(
        const float* __restrict__ x,
        const float* __restrict__ gamma,
        const float* __restrict__ beta,
        const uint32* __restrict__ amax_x_bits,
        uint32* __restrict__ amax_y_bits,
        float* __restrict__ mu_arr,
        float* __restrict__ is_arr) {
    const int row = blockIdx.x;
    const float* xr = x + (long long)row * NCOL;
    const float scale_in = fmaxf(__uint_as_float(*amax_x_bits) / 127.0f, 1e-8f);

    // load the whole row into registers: 4 float4 chunks per thread
    float xs[16];
    #pragma unroll
    for (int j = 0; j < 4; ++j) {
        const int col = j * 1024 + threadIdx.x * 4;
        const float4 v = *reinterpret_cast<const float4*>(xr + col);
        xs[j * 4 + 0] = v.x; xs[j * 4 + 1] = v.y;
        xs[j * 4 + 2] = v.z; xs[j * 4 + 3] = v.w;
    }

    // integer sums: Sx exact (|Sx| <= 127*4096 < 2^24), Sxx exact in int32
    int sx = 0, sxx = 0;
    #pragma unroll
    for (int e = 0; e < 16; ++e) {
        float q = rintf(xs[e] / scale_in);            // IEEE div + round-half-even
        q = fminf(fmaxf(q, -127.0f), 127.0f);
        const int qi = (int)q;
        sx += qi;
        sxx += qi * qi;
    }
    #pragma unroll
    for (int off = 32; off > 0; off >>= 1) {
        sx  += __shfl_down(sx, off);
        sxx += __shfl_down(sxx, off);
    }
    __shared__ int ssx[THREADS / 64], ssxx[THREADS / 64];
    const int lane = threadIdx.x & 63;
    const int w = threadIdx.x >> 6;
    if (lane == 0) { ssx[w] = sx; ssxx[w] = sxx; }
    __syncthreads();
    const int Sx  = ssx[0] + ssx[1] + ssx[2] + ssx[3];
    const int Sxx = ssxx[0] + ssxx[1] + ssxx[2] + ssxx[3];

    // moments (all threads redundantly — cheap, keeps values in registers)
    const float Ex  = (float)Sx * scale_in;
    const float Ex2 = (float)Sxx * (scale_in * scale_in);
    const float mu  = Ex * (1.0f / NCOL);                       // pow2: exact
    const float var = fmaxf(Ex2 * (1.0f / NCOL) - mu * mu, 0.0f);
    const float vi_f = fminf(fmaxf(rintf(var), 1.0f), 65535.0f);
    const int d = (int)vi_f;

    // exact replication of the reference LUT integer sqrt (rounded)
    const int msb = 31 - __clz(d);
    const int sh = 7 - (msb >> 1);
    const int dnorm = d << (sh * 2);
    const int lut = (dnorm >> 8) & 255;
    const int v2 = lut * 256 + 128;
    int mant = (int)__fsqrt_rn((float)v2);
    while (mant * mant > v2) --mant;
    while ((mant + 1) * (mant + 1) <= v2) ++mant;
    const int qf = mant >> sh;
    const int std_i = (d > qf * qf + qf) ? qf + 1 : qf;
    const float inv_std = 1.0f / fmaxf((float)std_i, 1e-5f);

    // per-row max|y| (y recomputed identically in k_output)
    float ymax = 0.0f;
    #pragma unroll
    for (int j = 0; j < 4; ++j) {
        const int col = j * 1024 + threadIdx.x * 4;
        const float4 g = *reinterpret_cast<const float4*>(gamma + col);
        const float4 b = *reinterpret_cast<const float4*>(beta + col);
        ymax = fmaxf(ymax, fabsf(norm_y(xs[j*4+0], mu, inv_std, g.x, b.x)));
        ymax = fmaxf(ymax, fabsf(norm_y(xs[j*4+1], mu, inv_std, g.y, b.y)));
        ymax = fmaxf(ymax, fabsf(norm_y(xs[j*4+2], mu, inv_std, g.z, b.z)));
        ymax = fmaxf(ymax, fabsf(norm_y(xs[j*4+3], mu, inv_std, g.w, b.w)));
    }
    ymax = wave_max_f(ymax);
    __shared__ float sy[THREADS / 64];
    if (lane == 0) sy[w] = ymax;
    __syncthreads();
    if (threadIdx.x == 0) {
        const float bm = fmaxf(fmaxf(sy[0], sy[1]), fmaxf(sy[2], sy[3]));
        atomicMax(amax_y_bits, __float_as_uint(bm));
        mu_arr[row] = mu;
        is_arr[row] = inv_std;
    }
}

// ---------------- kernel 3: normalize + requantize + store ----------------
__global__ void __launch_bounds__(THREADS) k_output(
        const float* __restrict__ x,
        const float* __restrict__ gamma,
        const float* __restrict__ beta,
        const float* __restrict__ mu_arr,
        const float* __restrict__ is_arr,
        const uint32* __restrict__ amax_y_bits,
        float* __restrict__ out) {
    const int row = blockIdx.x;
    const float mu = mu_arr[row];
    const float inv_std = is_arr[row];
    const float scale_out = fmaxf(__uint_as_float(*amax_y_bits) / 127.0f, 1e-8f);
    const float* xr = x + (long long)row * NCOL;
    float* orow = out + (long long)row * NCOL;
    #pragma unroll
    for (int j = 0; j < 4; ++j) {
        const int col = j * 1024 + threadIdx.x * 4;
        const float4 v = *reinterpret_cast<const float4*>(xr + col);
        const float4 g = *reinterpret_cast<const float4*>(gamma + col);
        const float4 b = *reinterpret_cast<const float4*>(beta + col);
        float4 o;
        {
            float q = fminf(fmaxf(rintf(norm_y(v.x, mu, inv_std, g.x, b.x) / scale_out), -127.0f), 127.0f);
            o.x = q * scale_out;
        }
        {
            float q = fminf(fmaxf(rintf(norm_y(v.y, mu, inv_std, g.y, b.y) / scale_out), -127.0f), 127.0f);
            o.y = q * scale_out;
        }
        {
            float q = fminf(fmaxf(rintf(norm_y(v.z, mu, inv_std, g.z, b.z) / scale_out), -127.0f), 127.0f);
            o.z = q * scale_out;
        }
        {
            float q = fminf(fmaxf(rintf(norm_y(v.w, mu, inv_std, g.w, b.w) / scale_out), -127.0f), 127.0f);
            o.w = q * scale_out;
        }
        *reinterpret_cast<float4*>(orow + col) = o;
    }
}

extern "C" void kernel_launch(void* const* d_in, const int* in_sizes, int n_in,
                              void* d_out, int out_size, void* d_ws, size_t ws_size,
                              hipStream_t stream) {
    const float* x     = (const float*)d_in[0];
    const float* gamma = (const float*)d_in[1];
    const float* beta  = (const float*)d_in[2];
    float* out = (float*)d_out;

    const long long n = (long long)in_sizes[0];
    const int rows = (int)(n / NCOL);

    // workspace layout: [0]=amax_x bits, [1]=amax_y bits, pad, mu[rows], inv_std[rows]
    uint32* amax_x = (uint32*)d_ws;
    uint32* amax_y = amax_x + 1;
    float* mu_arr = (float*)d_ws + 4;
    float* is_arr = mu_arr + rows;

    hipMemsetAsync(d_ws, 0, 16, stream);   // zero the two amax accumulators

    k_amax<<<2048, THREADS, 0, stream>>>(x, n, amax_x);
    k_rowstats<<<rows, THREADS, 0, stream>>>(x, gamma, beta, amax_x, amax_y,
                                             mu_arr, is_arr);
    k_output<<<rows, THREADS, 0, stream>>>(x, gamma, beta, mu_arr, is_arr,
                                           amax_y, out);
}

// Round 2
// 361.334 us; speedup vs baseline: 1.0052x; 1.0052x over previous
//
#include <hip/hip_runtime.h>

typedef unsigned int uint32;

static constexpr int NCOL = 4096;       // last-dim size (fixed by problem)
static constexpr int THREADS = 256;     // 4 waves/block

// --- shared y computation: must be identical between rowstats & output ---
__device__ __forceinline__ float norm_y(float x, float mu, float inv_std,
                                        float g, float b) {
    float xn = (x - mu) * inv_std;
    return xn * g + b;
}

__device__ __forceinline__ float wave_max_f(float m) {
    #pragma unroll
    for (int off = 32; off > 0; off >>= 1)
        m = fmaxf(m, __shfl_down(m, off));
    return m;
}

// ---------------- kernel 1: global amax(|x|) ----------------
__global__ void __launch_bounds__(THREADS) k_amax(const float* __restrict__ x,
                                                  long long n,
                                                  uint32* __restrict__ amax_bits) {
    long long i0 = ((long long)blockIdx.x * THREADS + threadIdx.x) * 4;
    long long stride = (long long)gridDim.x * THREADS * 4;
    float m = 0.0f;
    for (long long i = i0; i < n; i += stride) {
        const float4 v = *reinterpret_cast<const float4*>(x + i);
        m = fmaxf(m, fmaxf(fmaxf(fabsf(v.x), fabsf(v.y)),
                           fmaxf(fabsf(v.z), fabsf(v.w))));
    }
    m = wave_max_f(m);
    __shared__ float sm[THREADS / 64];
    const int lane = threadIdx.x & 63;
    const int w = threadIdx.x >> 6;
    if (lane == 0) sm[w] = m;
    __syncthreads();
    if (threadIdx.x == 0) {
        float bm = fmaxf(fmaxf(sm[0], sm[1]), fmaxf(sm[2], sm[3]));
        atomicMax(amax_bits, __float_as_uint(bm));
    }
}

// ---------------- kernel 2: per-row stats + global amax(|y|) ----------------
__global__ void __launch_bounds__(THREADS) k_rowstats(
        const float* __restrict__ x,
        const float* __restrict__ gamma,
        const float* __restrict__ beta,
        const uint32* __restrict__ amax_x_bits,
        uint32* __restrict__ amax_y_bits,
        float* __restrict__ mu_arr,
        float* __restrict__ is_arr) {
    const int row = blockIdx.x;
    const float* xr = x + (long long)row * NCOL;
    const float scale_in = fmaxf(__uint_as_float(*amax_x_bits) / 127.0f, 1e-8f);
    const float r_in = 1.0f / scale_in;   // ONE IEEE division; hot loop multiplies

    // load the whole row into registers: 4 float4 chunks per thread
    float xs[16];
    #pragma unroll
    for (int j = 0; j < 4; ++j) {
        const int col = j * 1024 + threadIdx.x * 4;
        const float4 v = *reinterpret_cast<const float4*>(xr + col);
        xs[j * 4 + 0] = v.x; xs[j * 4 + 1] = v.y;
        xs[j * 4 + 2] = v.z; xs[j * 4 + 3] = v.w;
    }

    // integer sums: Sx exact (|Sx| <= 127*4096 < 2^24), Sxx exact in int32
    int sx = 0, sxx = 0;
    #pragma unroll
    for (int e = 0; e < 16; ++e) {
        float q = rintf(xs[e] * r_in);                // mul instead of IEEE div
        q = fminf(fmaxf(q, -127.0f), 127.0f);
        const int qi = (int)q;
        sx += qi;
        sxx += qi * qi;
    }
    #pragma unroll
    for (int off = 32; off > 0; off >>= 1) {
        sx  += __shfl_down(sx, off);
        sxx += __shfl_down(sxx, off);
    }
    __shared__ int ssx[THREADS / 64], ssxx[THREADS / 64];
    const int lane = threadIdx.x & 63;
    const int w = threadIdx.x >> 6;
    if (lane == 0) { ssx[w] = sx; ssxx[w] = sxx; }
    __syncthreads();
    const int Sx  = ssx[0] + ssx[1] + ssx[2] + ssx[3];
    const int Sxx = ssxx[0] + ssxx[1] + ssxx[2] + ssxx[3];

    // moments (all threads redundantly — cheap, keeps values in registers)
    const float Ex  = (float)Sx * scale_in;
    const float Ex2 = (float)Sxx * (scale_in * scale_in);
    const float mu  = Ex * (1.0f / NCOL);                       // pow2: exact
    const float var = fmaxf(Ex2 * (1.0f / NCOL) - mu * mu, 0.0f);
    const float vi_f = fminf(fmaxf(rintf(var), 1.0f), 65535.0f);
    const int d = (int)vi_f;

    // exact replication of the reference LUT integer sqrt (rounded)
    const int msb = 31 - __clz(d);
    const int sh = 7 - (msb >> 1);
    const int dnorm = d << (sh * 2);
    const int lut = (dnorm >> 8) & 255;
    const int v2 = lut * 256 + 128;
    int mant = (int)__fsqrt_rn((float)v2);
    while (mant * mant > v2) --mant;
    while ((mant + 1) * (mant + 1) <= v2) ++mant;
    const int qf = mant >> sh;
    const int std_i = (d > qf * qf + qf) ? qf + 1 : qf;
    const float inv_std = 1.0f / fmaxf((float)std_i, 1e-5f);

    // per-row max|y| (y recomputed identically in k_output)
    float ymax = 0.0f;
    #pragma unroll
    for (int j = 0; j < 4; ++j) {
        const int col = j * 1024 + threadIdx.x * 4;
        const float4 g = *reinterpret_cast<const float4*>(gamma + col);
        const float4 b = *reinterpret_cast<const float4*>(beta + col);
        ymax = fmaxf(ymax, fabsf(norm_y(xs[j*4+0], mu, inv_std, g.x, b.x)));
        ymax = fmaxf(ymax, fabsf(norm_y(xs[j*4+1], mu, inv_std, g.y, b.y)));
        ymax = fmaxf(ymax, fabsf(norm_y(xs[j*4+2], mu, inv_std, g.z, b.z)));
        ymax = fmaxf(ymax, fabsf(norm_y(xs[j*4+3], mu, inv_std, g.w, b.w)));
    }
    ymax = wave_max_f(ymax);
    __shared__ float sy[THREADS / 64];
    if (lane == 0) sy[w] = ymax;
    __syncthreads();
    if (threadIdx.x == 0) {
        const float bm = fmaxf(fmaxf(sy[0], sy[1]), fmaxf(sy[2], sy[3]));
        atomicMax(amax_y_bits, __float_as_uint(bm));
        mu_arr[row] = mu;
        is_arr[row] = inv_std;
    }
}

// ---------------- kernel 3: normalize + requantize + store ----------------
__global__ void __launch_bounds__(THREADS) k_output(
        const float* __restrict__ x,
        const float* __restrict__ gamma,
        const float* __restrict__ beta,
        const float* __restrict__ mu_arr,
        const float* __restrict__ is_arr,
        const uint32* __restrict__ amax_y_bits,
        float* __restrict__ out) {
    const int row = blockIdx.x;
    const float mu = mu_arr[row];
    const float inv_std = is_arr[row];
    const float scale_out = fmaxf(__uint_as_float(*amax_y_bits) / 127.0f, 1e-8f);
    const float r_out = 1.0f / scale_out;  // ONE IEEE division per thread
    const float* xr = x + (long long)row * NCOL;
    float* orow = out + (long long)row * NCOL;
    #pragma unroll
    for (int j = 0; j < 4; ++j) {
        const int col = j * 1024 + threadIdx.x * 4;
        const float4 v = *reinterpret_cast<const float4*>(xr + col);
        const float4 g = *reinterpret_cast<const float4*>(gamma + col);
        const float4 b = *reinterpret_cast<const float4*>(beta + col);
        float4 o;
        {
            float q = fminf(fmaxf(rintf(norm_y(v.x, mu, inv_std, g.x, b.x) * r_out), -127.0f), 127.0f);
            o.x = q * scale_out;
        }
        {
            float q = fminf(fmaxf(rintf(norm_y(v.y, mu, inv_std, g.y, b.y) * r_out), -127.0f), 127.0f);
            o.y = q * scale_out;
        }
        {
            float q = fminf(fmaxf(rintf(norm_y(v.z, mu, inv_std, g.z, b.z) * r_out), -127.0f), 127.0f);
            o.z = q * scale_out;
        }
        {
            float q = fminf(fmaxf(rintf(norm_y(v.w, mu, inv_std, g.w, b.w) * r_out), -127.0f), 127.0f);
            o.w = q * scale_out;
        }
        *reinterpret_cast<float4*>(orow + col) = o;
    }
}

extern "C" void kernel_launch(void* const* d_in, const int* in_sizes, int n_in,
                              void* d_out, int out_size, void* d_ws, size_t ws_size,
                              hipStream_t stream) {
    const float* x     = (const float*)d_in[0];
    const float* gamma = (const float*)d_in[1];
    const float* beta  = (const float*)d_in[2];
    float* out = (float*)d_out;

    const long long n = (long long)in_sizes[0];
    const int rows = (int)(n / NCOL);

    // workspace layout: [0]=amax_x bits, [1]=amax_y bits, pad, mu[rows], inv_std[rows]
    uint32* amax_x = (uint32*)d_ws;
    uint32* amax_y = amax_x + 1;
    float* mu_arr = (float*)d_ws + 4;
    float* is_arr = mu_arr + rows;

    hipMemsetAsync(d_ws, 0, 16, stream);   // zero the two amax accumulators

    k_amax<<<2048, THREADS, 0, stream>>>(x, n, amax_x);
    k_rowstats<<<rows, THREADS, 0, stream>>>(x, gamma, beta, amax_x, amax_y,
                                             mu_arr, is_arr);
    k_output<<<rows, THREADS, 0, stream>>>(x, gamma, beta, mu_arr, is_arr,
                                           amax_y, out);
}

// Round 4
// 275.899 us; speedup vs baseline: 1.3165x; 1.3097x over previous
//
#include <hip/hip_runtime.h>

static constexpr int NCOL = 4096;       // last-dim size (fixed by problem)
static constexpr int THREADS = 256;     // 4 waves/block

typedef float v4f __attribute__((ext_vector_type(4)));  // for nontemporal stores

// --- shared y computation: must be identical between rowstats & output ---
__device__ __forceinline__ float norm_y(float x, float mu, float inv_std,
                                        float g, float b) {
    float xn = (x - mu) * inv_std;
    return xn * g + b;
}

__device__ __forceinline__ float wave_max_f(float m) {
    #pragma unroll
    for (int off = 32; off > 0; off >>= 1)
        m = fmaxf(m, __shfl_down(m, off));
    return m;
}

// ---------------- kernel 1: per-block partial amax(|x|), NO atomics ----------------
__global__ void __launch_bounds__(THREADS) k_amax(const float* __restrict__ x,
                                                  long long n,
                                                  float* __restrict__ partials) {
    const long long stride = (long long)gridDim.x * THREADS * 4;
    long long i0 = ((long long)blockIdx.x * THREADS + threadIdx.x) * 4;
    float m = 0.0f;
    // 4-deep unroll: 4 float4 loads in flight per iteration
    for (long long i = i0; i < n; i += 4 * stride) {
        float4 v0 = *reinterpret_cast<const float4*>(x + i);
        float4 v1, v2, v3;
        bool b1 = i + stride < n, b2 = i + 2 * stride < n, b3 = i + 3 * stride < n;
        if (b1) v1 = *reinterpret_cast<const float4*>(x + i + stride);
        if (b2) v2 = *reinterpret_cast<const float4*>(x + i + 2 * stride);
        if (b3) v3 = *reinterpret_cast<const float4*>(x + i + 3 * stride);
        m = fmaxf(m, fmaxf(fmaxf(fabsf(v0.x), fabsf(v0.y)),
                           fmaxf(fabsf(v0.z), fabsf(v0.w))));
        if (b1) m = fmaxf(m, fmaxf(fmaxf(fabsf(v1.x), fabsf(v1.y)),
                                   fmaxf(fabsf(v1.z), fabsf(v1.w))));
        if (b2) m = fmaxf(m, fmaxf(fmaxf(fabsf(v2.x), fabsf(v2.y)),
                                   fmaxf(fabsf(v2.z), fabsf(v2.w))));
        if (b3) m = fmaxf(m, fmaxf(fmaxf(fabsf(v3.x), fabsf(v3.y)),
                                   fmaxf(fabsf(v3.z), fabsf(v3.w))));
    }
    m = wave_max_f(m);
    __shared__ float sm[THREADS / 64];
    const int lane = threadIdx.x & 63;
    const int w = threadIdx.x >> 6;
    if (lane == 0) sm[w] = m;
    __syncthreads();
    if (threadIdx.x == 0) {
        partials[blockIdx.x] = fmaxf(fmaxf(sm[0], sm[1]), fmaxf(sm[2], sm[3]));
    }
}

// ---------------- tiny single-block max-reduce: partials[n] -> out[0] ----------------
__global__ void __launch_bounds__(THREADS) k_reduce(const float* __restrict__ partials,
                                                    int n, float* __restrict__ out) {
    float m = 0.0f;
    for (int i = threadIdx.x * 4; i < n; i += THREADS * 4) {
        const float4 v = *reinterpret_cast<const float4*>(partials + i);
        m = fmaxf(m, fmaxf(fmaxf(v.x, v.y), fmaxf(v.z, v.w)));
    }
    m = wave_max_f(m);
    __shared__ float sm[THREADS / 64];
    const int lane = threadIdx.x & 63;
    const int w = threadIdx.x >> 6;
    if (lane == 0) sm[w] = m;
    __syncthreads();
    if (threadIdx.x == 0)
        out[0] = fmaxf(fmaxf(sm[0], sm[1]), fmaxf(sm[2], sm[3]));
}

// ---------------- kernel 2: per-row stats + per-row max|y| (NO atomics) ----------------
__global__ void __launch_bounds__(THREADS) k_rowstats(
        const float* __restrict__ x,
        const float* __restrict__ gamma,
        const float* __restrict__ beta,
        const float* __restrict__ amax_x,
        float* __restrict__ rowmax_y,
        float* __restrict__ mu_arr,
        float* __restrict__ is_arr) {
    const int row = blockIdx.x;
    const float* xr = x + (long long)row * NCOL;
    const float scale_in = fmaxf(*amax_x / 127.0f, 1e-8f);
    const float r_in = 1.0f / scale_in;   // one IEEE division; hot loop multiplies

    // issue ALL loads up front: 4 float4 of x + 4+4 of gamma/beta (12 in flight)
    float xs[16];
    float4 gf[4], bf[4];
    #pragma unroll
    for (int j = 0; j < 4; ++j) {
        const int col = j * 1024 + threadIdx.x * 4;
        const float4 v = *reinterpret_cast<const float4*>(xr + col);
        xs[j * 4 + 0] = v.x; xs[j * 4 + 1] = v.y;
        xs[j * 4 + 2] = v.z; xs[j * 4 + 3] = v.w;
    }
    #pragma unroll
    for (int j = 0; j < 4; ++j) {
        const int col = j * 1024 + threadIdx.x * 4;
        gf[j] = *reinterpret_cast<const float4*>(gamma + col);
        bf[j] = *reinterpret_cast<const float4*>(beta + col);
    }

    // integer sums: Sx exact (|Sx| <= 127*4096 < 2^24), Sxx exact in int32
    int sx = 0, sxx = 0;
    #pragma unroll
    for (int e = 0; e < 16; ++e) {
        float q = rintf(xs[e] * r_in);
        q = fminf(fmaxf(q, -127.0f), 127.0f);
        const int qi = (int)q;
        sx += qi;
        sxx += qi * qi;
    }
    #pragma unroll
    for (int off = 32; off > 0; off >>= 1) {
        sx  += __shfl_down(sx, off);
        sxx += __shfl_down(sxx, off);
    }
    __shared__ int ssx[THREADS / 64], ssxx[THREADS / 64];
    const int lane = threadIdx.x & 63;
    const int w = threadIdx.x >> 6;
    if (lane == 0) { ssx[w] = sx; ssxx[w] = sxx; }
    __syncthreads();
    const int Sx  = ssx[0] + ssx[1] + ssx[2] + ssx[3];
    const int Sxx = ssxx[0] + ssxx[1] + ssxx[2] + ssxx[3];

    // moments (all threads redundantly — cheap, keeps values in registers)
    const float Ex  = (float)Sx * scale_in;
    const float Ex2 = (float)Sxx * (scale_in * scale_in);
    const float mu  = Ex * (1.0f / NCOL);                       // pow2: exact
    const float var = fmaxf(Ex2 * (1.0f / NCOL) - mu * mu, 0.0f);
    const float vi_f = fminf(fmaxf(rintf(var), 1.0f), 65535.0f);
    const int d = (int)vi_f;

    // exact replication of the reference LUT integer sqrt (rounded)
    const int msb = 31 - __clz(d);
    const int sh = 7 - (msb >> 1);
    const int dnorm = d << (sh * 2);
    const int lut = (dnorm >> 8) & 255;
    const int v2 = lut * 256 + 128;
    int mant = (int)__fsqrt_rn((float)v2);
    while (mant * mant > v2) --mant;
    while ((mant + 1) * (mant + 1) <= v2) ++mant;
    const int qf = mant >> sh;
    const int std_i = (d > qf * qf + qf) ? qf + 1 : qf;
    const float inv_std = 1.0f / fmaxf((float)std_i, 1e-5f);

    // per-row max|y| (y recomputed identically in k_output)
    float ymax = 0.0f;
    #pragma unroll
    for (int j = 0; j < 4; ++j) {
        ymax = fmaxf(ymax, fabsf(norm_y(xs[j*4+0], mu, inv_std, gf[j].x, bf[j].x)));
        ymax = fmaxf(ymax, fabsf(norm_y(xs[j*4+1], mu, inv_std, gf[j].y, bf[j].y)));
        ymax = fmaxf(ymax, fabsf(norm_y(xs[j*4+2], mu, inv_std, gf[j].z, bf[j].z)));
        ymax = fmaxf(ymax, fabsf(norm_y(xs[j*4+3], mu, inv_std, gf[j].w, bf[j].w)));
    }
    ymax = wave_max_f(ymax);
    __shared__ float sy[THREADS / 64];
    if (lane == 0) sy[w] = ymax;
    __syncthreads();
    if (threadIdx.x == 0) {
        rowmax_y[row] = fmaxf(fmaxf(sy[0], sy[1]), fmaxf(sy[2], sy[3]));
        mu_arr[row] = mu;
        is_arr[row] = inv_std;
    }
}

// ---------------- kernel 3: normalize + requantize + store ----------------
__global__ void __launch_bounds__(THREADS) k_output(
        const float* __restrict__ x,
        const float* __restrict__ gamma,
        const float* __restrict__ beta,
        const float* __restrict__ mu_arr,
        const float* __restrict__ is_arr,
        const float* __restrict__ amax_y,
        float* __restrict__ out) {
    const int row = blockIdx.x;
    const float mu = mu_arr[row];
    const float inv_std = is_arr[row];
    const float scale_out = fmaxf(*amax_y / 127.0f, 1e-8f);
    const float r_out = 1.0f / scale_out;  // one IEEE division per thread
    const float* xr = x + (long long)row * NCOL;
    float* orow = out + (long long)row * NCOL;
    #pragma unroll
    for (int j = 0; j < 4; ++j) {
        const int col = j * 1024 + threadIdx.x * 4;
        const float4 v = *reinterpret_cast<const float4*>(xr + col);
        const float4 g = *reinterpret_cast<const float4*>(gamma + col);
        const float4 b = *reinterpret_cast<const float4*>(beta + col);
        v4f o;
        {
            float q = fminf(fmaxf(rintf(norm_y(v.x, mu, inv_std, g.x, b.x) * r_out), -127.0f), 127.0f);
            o.x = q * scale_out;
        }
        {
            float q = fminf(fmaxf(rintf(norm_y(v.y, mu, inv_std, g.y, b.y) * r_out), -127.0f), 127.0f);
            o.y = q * scale_out;
        }
        {
            float q = fminf(fmaxf(rintf(norm_y(v.z, mu, inv_std, g.z, b.z) * r_out), -127.0f), 127.0f);
            o.z = q * scale_out;
        }
        {
            float q = fminf(fmaxf(rintf(norm_y(v.w, mu, inv_std, g.w, b.w) * r_out), -127.0f), 127.0f);
            o.w = q * scale_out;
        }
        // non-temporal: out is never re-read; don't evict x from L2/L3
        __builtin_nontemporal_store(o, reinterpret_cast<v4f*>(orow + col));
    }
}

extern "C" void kernel_launch(void* const* d_in, const int* in_sizes, int n_in,
                              void* d_out, int out_size, void* d_ws, size_t ws_size,
                              hipStream_t stream) {
    const float* x     = (const float*)d_in[0];
    const float* gamma = (const float*)d_in[1];
    const float* beta  = (const float*)d_in[2];
    float* out = (float*)d_out;

    const long long n = (long long)in_sizes[0];
    const int rows = (int)(n / NCOL);
    const int AMAX_BLOCKS = 2048;

    // workspace layout (floats): [0]=amax_x, [1]=amax_y, pad to 16,
    // partials_x[2048], rowmax_y[rows], mu[rows], inv_std[rows]
    float* ws = (float*)d_ws;
    float* amax_x   = ws + 0;
    float* amax_y   = ws + 1;
    float* px       = ws + 16;
    float* rowmax_y = px + AMAX_BLOCKS;
    float* mu_arr   = rowmax_y + rows;
    float* is_arr   = mu_arr + rows;

    k_amax<<<AMAX_BLOCKS, THREADS, 0, stream>>>(x, n, px);
    k_reduce<<<1, THREADS, 0, stream>>>(px, AMAX_BLOCKS, amax_x);
    k_rowstats<<<rows, THREADS, 0, stream>>>(x, gamma, beta, amax_x,
                                             rowmax_y, mu_arr, is_arr);
    k_reduce<<<1, THREADS, 0, stream>>>(rowmax_y, rows, amax_y);
    k_output<<<rows, THREADS, 0, stream>>>(x, gamma, beta, mu_arr, is_arr,
                                           amax_y, out);
}